// Round 1
// baseline (429.698 us; speedup 1.0000x reference)
//
#include <hip/hip_runtime.h>
#include <hip/hip_cooperative_groups.h>

namespace cg = cooperative_groups;

// Problem: B=2, S=2048, E=1024, H=16, D=64. ALL FP32 (in and out).
// Reference einsum 'bhqk,bvhd->bqhd' sums k and v SEPARATELY:
//   out[b,q,h,d] = (sum_k softmax) * (sum_s v[b,s,h,d]) = sum_s v[b,s,h,d]
// => out_row[b,:] = colsum(values[b]) @ Wv^T + S*bv, broadcast over all q.
// Q/K path mathematically dead (softmax rows sum to 1).
//
// Evidence ledger:
//  R0 (out=0):   err=106.5 = max|ref|  -> ref IS the separate-sum field.
//  R1 (bf16 in): err=NaN              -> inputs are fp32.
//  R2==R3 (bf16 out): err=173.5 identical -> bf16-in-fp32-buffer scramble.
//  R4 (4-dispatch fp32, prev session): 121.1 us; re-bench 124.3 us.
//    rocprof: top-5 dispatches are ALL harness fillBufferAligned
//    (256 MiB @ ~41 us each, 78-84% HBM peak) summing to ~the whole
//    measured window. Our kernels ~15 us total by traffic arithmetic.
//  This round: single cooperative kernel (1 dispatch, 3 grid.sync,
//    no atomics, no memset) to strip dispatch overhead and measure the
//    harness floor. If dur_us is unchanged -> harness-fill roofline.

#define BB 2
#define SS 2048
#define EE 1024

constexpr int GRID = 1024;          // 4 blocks/CU on 256 CUs — co-resident
constexpr int BLK  = 256;
constexpr int NSC  = GRID / BB;     // 512 s-chunks per batch
constexpr int SC   = SS / NSC;      // 4 rows per chunk

__global__ void __launch_bounds__(BLK, 4) fused_kernel(
    const float* __restrict__ values,
    const float* __restrict__ Wv,
    const float* __restrict__ bv,
    float* __restrict__ out,
    float* __restrict__ ws)
{
    cg::grid_group grid = cg::this_grid();
    const int tid = threadIdx.x;
    const int g   = blockIdx.x;

    float* partials = ws;                       // GRID*EE floats (4 MB)
    float* colsum   = ws + (size_t)GRID * EE;   // BB*EE
    float* out_row  = colsum + BB * EE;         // BB*EE

    // ---- Phase 1: per-block partial column sums (no atomics) ----
    {
        const int b  = g >> 9;                  // g / NSC
        const int sc = g & (NSC - 1);
        const float* p = values + (size_t)b * SS * EE
                                + (size_t)sc * SC * EE + tid * 4;
        float4 a = {0.f, 0.f, 0.f, 0.f};
        #pragma unroll
        for (int s = 0; s < SC; ++s) {
            float4 u = *reinterpret_cast<const float4*>(p + (size_t)s * EE);
            a.x += u.x; a.y += u.y; a.z += u.z; a.w += u.w;
        }
        *reinterpret_cast<float4*>(partials + (size_t)g * EE + tid * 4) = a;
    }
    grid.sync();

    // ---- Phase 2: reduce partials -> colsum (first 2048 threads) ----
    {
        const int t = g * BLK + tid;
        if (t < BB * EE) {
            const int b = t >> 10;
            const int e = t & (EE - 1);
            const float* pp = partials + (size_t)b * NSC * EE + e;
            float s0 = 0.f, s1 = 0.f, s2 = 0.f, s3 = 0.f;
            #pragma unroll 4
            for (int sc = 0; sc < NSC; sc += 4) {
                s0 += pp[(size_t)(sc + 0) * EE];
                s1 += pp[(size_t)(sc + 1) * EE];
                s2 += pp[(size_t)(sc + 2) * EE];
                s3 += pp[(size_t)(sc + 3) * EE];
            }
            colsum[t] = (s0 + s1) + (s2 + s3);
        }
    }
    grid.sync();

    // ---- Phase 3: out_row[b][j] = colsum[b] . Wv[j,:] + S*bv[j] ----
    {
        const int w    = (g * BLK + tid) >> 6;  // global wave id, [0,4096)
        const int lane = tid & 63;
        if (w < BB * EE) {
            const int b = w >> 10;
            const int j = w & (EE - 1);
            const float* wr = Wv + (size_t)j * EE;
            const float* x  = colsum + b * EE;
            float acc = 0.f;
            #pragma unroll
            for (int i = 0; i < EE / 256; ++i) {   // 4 iters, float4/lane
                int e = i * 256 + lane * 4;
                float4 wv = *reinterpret_cast<const float4*>(wr + e);
                float4 xv = *reinterpret_cast<const float4*>(x + e);
                acc += wv.x * xv.x + wv.y * xv.y + wv.z * xv.z + wv.w * xv.w;
            }
            #pragma unroll
            for (int off = 32; off; off >>= 1) acc += __shfl_down(acc, off, 64);
            if (lane == 0) out_row[w] = acc + (float)SS * bv[j];
        }
    }
    grid.sync();

    // ---- Phase 4: broadcast out_row across all q (fp32 stores) ----
    {
        // each block owns 4096 contiguous floats; 4096 | 2^21 so no b-straddle
        const size_t base = (size_t)g * ((size_t)BB * SS * EE / GRID); // *4096
        const int b = (int)(base >> 21);          // / (SS*EE)
        const float4 v =
            *reinterpret_cast<const float4*>(out_row + b * EE + tid * 4);
        float* o = out + base;
        #pragma unroll
        for (int i = 0; i < 4; ++i)
            *reinterpret_cast<float4*>(o + (size_t)i * 1024 + tid * 4) = v;
    }
}

extern "C" void kernel_launch(void* const* d_in, const int* in_sizes, int n_in,
                              void* d_out, int out_size, void* d_ws, size_t ws_size,
                              hipStream_t stream) {
    // setup_inputs order: values, keys, queries, Wv, bv, Wk, bk, Wq, bq
    const float* values = (const float*)d_in[0];
    const float* Wv     = (const float*)d_in[3];
    const float* bv     = (const float*)d_in[4];
    float* out = (float*)d_out;
    float* ws  = (float*)d_ws;

    void* args[] = { (void*)&values, (void*)&Wv, (void*)&bv,
                     (void*)&out, (void*)&ws };
    hipLaunchCooperativeKernel((void*)fused_kernel, dim3(GRID), dim3(BLK),
                               args, 0, stream);
}

// Round 2
// 122.383 us; speedup vs baseline: 3.5111x; 3.5111x over previous
//
#include <hip/hip_runtime.h>

// Problem: B=2, S=2048, E=1024, H=16, D=64. ALL FP32 (in and out).
// Reference einsum 'bhqk,bvhd->bqhd' sums k and v SEPARATELY:
//   out[b,q,h,d] = (sum_k softmax) * (sum_s v[b,s,h,d]) = sum_s v[b,s,h,d]
// => out_row[b,:] = colsum(values[b]) @ Wv^T + S*bv, broadcast over all q.
// Q/K path mathematically dead (softmax rows sum to 1).
//
// Evidence ledger:
//  R0 (out=0):   err=106.5 = max|ref|  -> ref IS the separate-sum field.
//  R1 (bf16 in): err=NaN              -> inputs are fp32.
//  R2==R3 (bf16 out): err=173.5 identical -> bf16-in-fp32-buffer scramble.
//  R4 (4-dispatch fp32): 121.1 us; re-bench 124.3 us. rocprof: top-5
//    dispatches all harness fillBufferAligned (256 MiB @ ~41 us each,
//    78-84% HBM peak), summing to ~the whole window. Our kernels ~15 us.
//  R5 (cooperative 1-dispatch, 3 grid.sync): 429.7 us REGRESSION.
//    fused_kernel alone 317 us @ 105 GB/s, VALUBusy 0.5% -> grid.sync()
//    spin on 1024 WGs across 8 non-coherent XCDs costs ~100 us/sync.
//    Cooperative launch is the wrong tool at this grid size.
//  This round: revert to the verified R4 4-dispatch structure. Our
//    on-GPU time (~15 us) is ~12% of the measured window; the rest is
//    harness poison fills we cannot influence. Expect dur_us 121-125.

#define BB 2
#define SS 2048
#define EE 1024

// ---------------- K1: colsum[b,e] = sum_s values[b,s,e] -------------------
constexpr int NSC = 128;       // s-chunks per batch
constexpr int SC  = SS / NSC;  // 16 rows per block

__global__ void colsum_kernel(const float* __restrict__ values,
                              float* __restrict__ colsum) {
    const int tid = threadIdx.x;         // 256 threads, 4 e's each
    const int b   = blockIdx.x % BB;
    const int sc  = blockIdx.x / BB;     // [0, NSC)
    const int e0  = tid * 4;
    const float* p =
        values + (size_t)b * SS * EE + (size_t)sc * SC * EE + e0;
    float a0 = 0.f, a1 = 0.f, a2 = 0.f, a3 = 0.f;
    #pragma unroll
    for (int s = 0; s < SC; ++s) {
        float4 u = *reinterpret_cast<const float4*>(p + (size_t)s * EE);
        a0 += u.x; a1 += u.y; a2 += u.z; a3 += u.w;
    }
    float* dst = colsum + b * EE + e0;
    atomicAdd(dst + 0, a0);
    atomicAdd(dst + 1, a1);
    atomicAdd(dst + 2, a2);
    atomicAdd(dst + 3, a3);
}

// ---------------- K2: out_row = colsum @ Wv^T + S*bv ----------------------
// One wave per output element j (torch Linear: y_j = sum_e x_e * W[j,e]).
__global__ void matvec_kernel(const float* __restrict__ Wv,
                              const float* __restrict__ bv,
                              const float* __restrict__ colsum,
                              float* __restrict__ out_row) {
    const int gtid = blockIdx.x * blockDim.x + threadIdx.x;
    const int wave = gtid >> 6;          // [0, 2048): (b, j)
    const int lane = threadIdx.x & 63;
    const int b = wave / EE;
    const int j = wave % EE;
    const float* w = Wv + (size_t)j * EE;    // row j of W
    const float* x = colsum + b * EE;
    float acc = 0.f;
    #pragma unroll
    for (int i = 0; i < EE / 256; ++i) {     // 4 iters, float4 per lane
        int e = i * 256 + lane * 4;
        float4 wv = *reinterpret_cast<const float4*>(w + e);
        float4 xv = *reinterpret_cast<const float4*>(x + e);
        acc += wv.x * xv.x + wv.y * xv.y + wv.z * xv.z + wv.w * xv.w;
    }
    #pragma unroll
    for (int off = 32; off; off >>= 1) acc += __shfl_down(acc, off, 64);
    if (lane == 0)
        out_row[b * EE + j] = acc + (float)SS * bv[j];
}

// ---------------- K3: broadcast out_row across all q, fp32 stores ---------
__global__ void bcast_kernel(const float* __restrict__ out_row,
                             float* __restrict__ out) {
    const size_t idx = (size_t)blockIdx.x * blockDim.x + threadIdx.x;
    const size_t pos = idx * 4;              // 4 floats (16 B) per thread
    const int e = (int)(pos & (EE - 1));     // pos % 1024, pos ≡ 0 mod 4
    const int b = (int)(pos / ((size_t)SS * EE));
    const float4 v = *reinterpret_cast<const float4*>(out_row + b * EE + e);
    *reinterpret_cast<float4*>(out + pos) = v;
}

extern "C" void kernel_launch(void* const* d_in, const int* in_sizes, int n_in,
                              void* d_out, int out_size, void* d_ws, size_t ws_size,
                              hipStream_t stream) {
    // setup_inputs order: values, keys, queries, Wv, bv, Wk, bk, Wq, bq
    const float* values = (const float*)d_in[0];
    const float* Wv     = (const float*)d_in[3];
    const float* bv     = (const float*)d_in[4];
    float* out = (float*)d_out;

    float* colsum  = (float*)d_ws;          // B*E floats
    float* out_row = colsum + BB * EE;      // B*E floats

    hipMemsetAsync(colsum, 0, BB * EE * sizeof(float), stream);

    colsum_kernel<<<BB * NSC, 256, 0, stream>>>(values, colsum);

    matvec_kernel<<<(BB * EE) / 4, 256, 0, stream>>>(Wv, bv, colsum, out_row);

    const size_t total = (size_t)BB * SS * EE;          // 4,194,304 floats
    bcast_kernel<<<(unsigned int)(total / 4 / 256), 256, 0, stream>>>(
        out_row, out);
}